// Round 5
// baseline (785.166 us; speedup 1.0000x reference)
//
#include <hip/hip_runtime.h>
#include <stdint.h>

// TiLinear: int8 GEMM [32768,1024] x [1024,1024]^T (int32 acc) -> global
// range-estimate -> round-shift requantize to int8 (stored as int32) + exp.
//
// Round 5: round-3 coarse K-loop structure (1 barrier/tile, 32.. now 16 MFMA
// per wave per barrier) with BK=64 so dbuf LDS = 64KB -> 2 blocks/CU.
// Occupancy-driven overlap (m97 mechanism) instead of barrier choreography
// (round 4 regressed). Swizzle for 64B rows: byte ^= ((row>>1)&3)<<4, which
// with the row-parity bit spreads each 8-row group over all 32 banks.

#define MM 32768
#define NN 1024
#define KK 1024
#define BM 256
#define BN 256
#define BK 64
#define NKT (KK / BK)  // 16

typedef __attribute__((ext_vector_type(4))) int i32x4;
typedef __attribute__((ext_vector_type(16))) int i32x16;

__device__ __forceinline__ int pack4(int a, int b, int c, int d) {
  return (int)((unsigned)(a & 0xff) | ((unsigned)(b & 0xff) << 8) |
               ((unsigned)(c & 0xff) << 16) | ((unsigned)(d & 0xff) << 24));
}

__global__ void k_init(unsigned* slot) {
  if (threadIdx.x == 0) *slot = 0u;
}

// Pack sign-extended-int8-in-int32 -> raw int8. n multiple of 16.
__global__ void k_pack(const int* __restrict__ src, int8_t* __restrict__ dst, int n) {
  long t = (long)blockIdx.x * blockDim.x + threadIdx.x;
  long stride = (long)gridDim.x * blockDim.x;
  for (long i = t * 16; i < (long)n; i += stride * 16) {
    const i32x4* s = (const i32x4*)(src + i);
    i32x4 a0 = s[0], a1 = s[1], a2 = s[2], a3 = s[3];
    i32x4 o;
    o[0] = pack4(a0[0], a0[1], a0[2], a0[3]);
    o[1] = pack4(a1[0], a1[1], a1[2], a1[3]);
    o[2] = pack4(a2[0], a2[1], a2[2], a2[3]);
    o[3] = pack4(a3[0], a3[1], a3[2], a3[3]);
    *(i32x4*)(dst + i) = o;
  }
}

// 256x256 tile, 8 waves (wm=w>>2: 128-row half; wn=w&3: 64-col slice),
// BK=64, dbuf 64KB -> 2 blocks/CU. acc[4][2] of 32x32 frags.
__global__ __launch_bounds__(512, 4)
void k_gemm(const int8_t* __restrict__ A8, const int8_t* __restrict__ B8,
            int* __restrict__ out, unsigned* __restrict__ maxslot) {
  __shared__ int8_t As[2][BM * BK];  // 16KB each
  __shared__ int8_t Bs[2][BN * BK];

  const int tid  = threadIdx.x;
  const int lane = tid & 63;
  const int w    = tid >> 6;
  const int wm   = w >> 2;  // 0..1 -> 128-row half
  const int wn   = w & 3;   // 0..3 -> 64-col slice

  // XCD-bijective swizzle: 512 wgs, 8 XCDs, 64-wg chunks (16 bm x 4 bn).
  const int orig = blockIdx.x;
  const int wgid = ((orig & 7) << 6) + (orig >> 3);
  const int bn = wgid & 3;
  const int bm = wgid >> 2;
  const int m0 = bm * BM;
  const int n0 = bn * BN;

  i32x16 acc[4][2];
#pragma unroll
  for (int i = 0; i < 4; ++i)
#pragma unroll
    for (int j = 0; j < 2; ++j) acc[i][j] = 0;

  // LDS layout (both tiles): physical byte p holds logical element at
  // (row = p>>6, col = (p&63) ^ ((row>>1 & 3)<<4)).  gload_lds dest is
  // linear; swizzle rides on the per-lane SOURCE address (rule 21).
  auto stage = [&](int buf, int kt) {
    const int k0 = kt * BK;
#pragma unroll
    for (int q = 0; q < 2; ++q) {
      const int p   = (w * 2 + q) * 1024 + lane * 16;
      const int row = p >> 6;
      const int col = (p & 63) ^ (((row >> 1) & 3) << 4);
      __builtin_amdgcn_global_load_lds(
          (const __attribute__((address_space(1))) void*)(A8 + (size_t)(m0 + row) * KK + k0 + col),
          (__attribute__((address_space(3))) void*)(&As[buf][(w * 2 + q) * 1024]),
          16, 0, 0);
      __builtin_amdgcn_global_load_lds(
          (const __attribute__((address_space(1))) void*)(B8 + (size_t)(n0 + row) * KK + k0 + col),
          (__attribute__((address_space(3))) void*)(&Bs[buf][(w * 2 + q) * 1024]),
          16, 0, 0);
    }
  };

  // 16 MFMA per wave per K-tile; 12 swizzled ds_read_b128 (conflict-free:
  // per 8-row group the XOR + row-parity covers all 32 banks).
  auto compute = [&](int buf) {
#pragma unroll
    for (int ks = 0; ks < 2; ++ks) {
      i32x4 af[4], bf[2];
#pragma unroll
      for (int ni = 0; ni < 2; ++ni) {
        const int row = wn * 64 + ni * 32 + (lane & 31);
        const int a = row * BK +
            ((ks * 32 + ((lane >> 5) << 4)) ^ (((row >> 1) & 3) << 4));
        bf[ni] = *(const i32x4*)(&Bs[buf][a]);
      }
#pragma unroll
      for (int mi = 0; mi < 4; ++mi) {
        const int row = wm * 128 + mi * 32 + (lane & 31);
        const int a = row * BK +
            ((ks * 32 + ((lane >> 5) << 4)) ^ (((row >> 1) & 3) << 4));
        af[mi] = *(const i32x4*)(&As[buf][a]);
      }
      __builtin_amdgcn_s_setprio(1);
#pragma unroll
      for (int mi = 0; mi < 4; ++mi)
#pragma unroll
        for (int ni = 0; ni < 2; ++ni)
          acc[mi][ni] = __builtin_amdgcn_mfma_i32_32x32x32_i8(
              af[mi], bf[ni], acc[mi][ni], 0, 0, 0);
      __builtin_amdgcn_s_setprio(0);
    }
  };

  stage(0, 0);
  __syncthreads();
  for (int kt = 0; kt < NKT; ++kt) {
    if (kt + 1 < NKT) stage((kt + 1) & 1, kt + 1);  // prefetch next tile
    compute(kt & 1);
    __syncthreads();  // drain; other resident block's compute covers it
  }

  // Wave max of |acc| -> atomicMax
  int mx = 0;
#pragma unroll
  for (int mi = 0; mi < 4; ++mi)
#pragma unroll
    for (int ni = 0; ni < 2; ++ni)
#pragma unroll
      for (int rg = 0; rg < 16; ++rg) {
        int x = acc[mi][ni][rg];
        int a = x < 0 ? -x : x;
        mx = a > mx ? a : mx;
      }
#pragma unroll
  for (int off = 32; off >= 1; off >>= 1) {
    int o = __shfl_xor(mx, off);
    mx = o > mx ? o : mx;
  }
  if (lane == 0) atomicMax(maxslot, (unsigned)mx);

  // Store raw acc (C/D map: col=lane&31, row=(rg&3)+8*(rg>>2)+4*(lane>>5))
#pragma unroll
  for (int mi = 0; mi < 4; ++mi)
#pragma unroll
    for (int ni = 0; ni < 2; ++ni) {
      const int mbase = m0 + wm * 128 + mi * 32;
      const int ncol  = n0 + wn * 64 + ni * 32 + (lane & 31);
#pragma unroll
      for (int rg = 0; rg < 16; ++rg) {
        const int mrow = mbase + (rg & 3) + ((rg >> 2) << 3) + ((lane >> 5) << 2);
        out[(size_t)mrow * NN + ncol] = acc[mi][ni][rg];
      }
    }
}

// Fallback (ws too small): reg-staged int32 GEMM, 128x128 tile, BK=128.
__global__ __launch_bounds__(256, 2)
void k_gemm_fb(const int* __restrict__ A32, const int* __restrict__ B32,
               int* __restrict__ out, unsigned* __restrict__ maxslot) {
  __shared__ int8_t As[128 * 128];
  __shared__ int8_t Bs[128 * 128];
  const int tid = threadIdx.x, lane = tid & 63, w = tid >> 6;
  const int wr = w >> 1, wc = w & 1;
  const int bn = blockIdx.x & 7, bm = blockIdx.x >> 3;
  const int m0 = bm * 128, n0 = bn * 128;
  i32x16 acc[2][2];
#pragma unroll
  for (int i = 0; i < 2; ++i)
#pragma unroll
    for (int j = 0; j < 2; ++j) acc[i][j] = 0;
  for (int kt = 0; kt < 8; ++kt) {
    const int k0 = kt * 128;
    __syncthreads();
#pragma unroll
    for (int j = 0; j < 4; ++j) {
      const int fb = (j * 256 + tid) * 16;
      const int row = fb >> 7;
      const int swz = fb ^ ((row & 7) << 4);
      const int col = fb & 127;
      const int* sa = A32 + (size_t)(m0 + row) * KK + k0 + col;
      const int* sb = B32 + (size_t)(n0 + row) * KK + k0 + col;
      i32x4 av, bv;
#pragma unroll
      for (int t = 0; t < 4; ++t) {
        i32x4 ta = ((const i32x4*)sa)[t];
        i32x4 tb = ((const i32x4*)sb)[t];
        av[t] = pack4(ta[0], ta[1], ta[2], ta[3]);
        bv[t] = pack4(tb[0], tb[1], tb[2], tb[3]);
      }
      *(i32x4*)(As + swz) = av;
      *(i32x4*)(Bs + swz) = bv;
    }
    __syncthreads();
#pragma unroll
    for (int ks = 0; ks < 4; ++ks) {
      i32x4 af[2], bf[2];
#pragma unroll
      for (int mi = 0; mi < 2; ++mi) {
        const int row = wr * 64 + mi * 32 + (lane & 31);
        int a = row * 128 + ks * 32 + ((lane >> 5) << 4);
        a ^= (row & 7) << 4;
        af[mi] = *(const i32x4*)(As + a);
      }
#pragma unroll
      for (int ni = 0; ni < 2; ++ni) {
        const int row = wc * 64 + ni * 32 + (lane & 31);
        int a = row * 128 + ks * 32 + ((lane >> 5) << 4);
        a ^= (row & 7) << 4;
        bf[ni] = *(const i32x4*)(Bs + a);
      }
#pragma unroll
      for (int mi = 0; mi < 2; ++mi)
#pragma unroll
        for (int ni = 0; ni < 2; ++ni)
          acc[mi][ni] = __builtin_amdgcn_mfma_i32_32x32x32_i8(
              af[mi], bf[ni], acc[mi][ni], 0, 0, 0);
    }
  }
  int mx = 0;
#pragma unroll
  for (int mi = 0; mi < 2; ++mi)
#pragma unroll
    for (int ni = 0; ni < 2; ++ni)
#pragma unroll
      for (int rg = 0; rg < 16; ++rg) {
        int x = acc[mi][ni][rg];
        int a = x < 0 ? -x : x;
        mx = a > mx ? a : mx;
      }
#pragma unroll
  for (int off = 32; off >= 1; off >>= 1) {
    int o = __shfl_xor(mx, off);
    mx = o > mx ? o : mx;
  }
  if (lane == 0) atomicMax(maxslot, (unsigned)mx);
#pragma unroll
  for (int mi = 0; mi < 2; ++mi)
#pragma unroll
    for (int ni = 0; ni < 2; ++ni) {
      const int mbase = m0 + wr * 64 + mi * 32;
      const int ncol = n0 + wc * 64 + ni * 32 + (lane & 31);
#pragma unroll
      for (int rg = 0; rg < 16; ++rg) {
        const int mrow = mbase + (rg & 3) + ((rg >> 2) << 3) + ((lane >> 5) << 2);
        out[(size_t)mrow * NN + ncol] = acc[mi][ni][rg];
      }
    }
}

// In-place requantize d_out[0..M*N) using max from maxslot. BW-bound.
__global__ __launch_bounds__(256)
void k_requant(int* __restrict__ out, const unsigned* __restrict__ maxslot) {
  const unsigned r = *maxslot;
  const int bits  = (r <= 1u) ? 0 : (32 - __clz((int)(r - 1u)));
  const int shift = bits - 7;  // BITWIDTH = 7
  const size_t n = (size_t)MM * NN;
  size_t i = ((size_t)blockIdx.x * blockDim.x + threadIdx.x) * 4;
  const size_t stride = (size_t)gridDim.x * blockDim.x * 4;
  if (shift > 0) {
    for (; i < n; i += stride) {
      i32x4 v = *(i32x4*)(out + i);
#pragma unroll
      for (int j = 0; j < 4; ++j) {
        const int x = v[j];
        int t = (x >> shift) + ((x >> (shift - 1)) & 1);
        v[j] = t > 127 ? 127 : (t < -127 ? -127 : t);
      }
      *(i32x4*)(out + i) = v;
    }
  } else {
    for (; i < n; i += stride) {
      i32x4 v = *(i32x4*)(out + i);
#pragma unroll
      for (int j = 0; j < 4; ++j) v[j] = (int)(int8_t)v[j];
      *(i32x4*)(out + i) = v;
    }
  }
}

__global__ void k_final(int* __restrict__ out, const int* __restrict__ exp_in,
                        const int* __restrict__ wexp) {
  if (threadIdx.x == 0) {
    const unsigned r = *(const unsigned*)(out + (size_t)MM * NN);
    const int bits  = (r <= 1u) ? 0 : (32 - __clz((int)(r - 1u)));
    const int shift = bits - 7;
    out[(size_t)MM * NN] = *exp_in + *wexp + (shift > 0 ? shift : 0);
  }
}

extern "C" void kernel_launch(void* const* d_in, const int* in_sizes, int n_in,
                              void* d_out, int out_size, void* d_ws, size_t ws_size,
                              hipStream_t stream) {
  const int* act    = (const int*)d_in[0];
  const int* wgt    = (const int*)d_in[1];
  const int* exp_in = (const int*)d_in[2];
  const int* wexp   = (const int*)d_in[3];
  int* out          = (int*)d_out;
  unsigned* maxslot = (unsigned*)(out + (size_t)MM * NN);  // spare exp slot

  const size_t need = (size_t)(MM + NN) * KK + 256;

  k_init<<<1, 64, 0, stream>>>(maxslot);

  if (ws_size >= need) {
    int8_t* a8 = (int8_t*)d_ws;
    int8_t* w8 = a8 + (size_t)MM * KK;
    k_pack<<<2048, 256, 0, stream>>>(act, a8, MM * KK);
    k_pack<<<256, 256, 0, stream>>>(wgt, w8, NN * KK);
    const int grid = (MM / BM) * (NN / BN);  // 512
    k_gemm<<<grid, 512, 0, stream>>>(a8, w8, out, maxslot);
  } else {
    k_gemm_fb<<<(MM / 128) * (NN / 128), 256, 0, stream>>>(act, wgt, out, maxslot);
  }

  k_requant<<<4096, 256, 0, stream>>>(out, maxslot);
  k_final<<<1, 64, 0, stream>>>(out, exp_in, wexp);
}

// Round 6
// 173.822 us; speedup vs baseline: 4.5171x; 4.5171x over previous
//
#include <hip/hip_runtime.h>
#include <stdint.h>

// TiLinear: int8 GEMM [32768,1024] x [1024,1024]^T (int32 acc) -> global
// range-estimate -> round-shift requantize to int8 (stored as int32) + exp.
//
// Round 6: round-5 structure (BK=64, 64KB dbuf LDS -> 2 blocks/CU) with the
// register cap fixed: __launch_bounds__(512, 2). Round 5's (512,4) capped
// waves at 128 unified regs -> acc spilled to scratch (3.5GB HBM traffic).
// 2 blocks/CU now comes from LDS (160/64=2), not a reg cap.

#define MM 32768
#define NN 1024
#define KK 1024
#define BM 256
#define BN 256
#define BK 64
#define NKT (KK / BK)  // 16

typedef __attribute__((ext_vector_type(4))) int i32x4;
typedef __attribute__((ext_vector_type(16))) int i32x16;

__device__ __forceinline__ int pack4(int a, int b, int c, int d) {
  return (int)((unsigned)(a & 0xff) | ((unsigned)(b & 0xff) << 8) |
               ((unsigned)(c & 0xff) << 16) | ((unsigned)(d & 0xff) << 24));
}

__global__ void k_init(unsigned* slot) {
  if (threadIdx.x == 0) *slot = 0u;
}

// Pack sign-extended-int8-in-int32 -> raw int8. n multiple of 16.
__global__ void k_pack(const int* __restrict__ src, int8_t* __restrict__ dst, int n) {
  long t = (long)blockIdx.x * blockDim.x + threadIdx.x;
  long stride = (long)gridDim.x * blockDim.x;
  for (long i = t * 16; i < (long)n; i += stride * 16) {
    const i32x4* s = (const i32x4*)(src + i);
    i32x4 a0 = s[0], a1 = s[1], a2 = s[2], a3 = s[3];
    i32x4 o;
    o[0] = pack4(a0[0], a0[1], a0[2], a0[3]);
    o[1] = pack4(a1[0], a1[1], a1[2], a1[3]);
    o[2] = pack4(a2[0], a2[1], a2[2], a2[3]);
    o[3] = pack4(a3[0], a3[1], a3[2], a3[3]);
    *(i32x4*)(dst + i) = o;
  }
}

// 256x256 tile, 8 waves (wm=w>>2: 128-row half; wn=w&3: 64-col slice),
// BK=64, dbuf 64KB -> 2 blocks/CU via LDS. acc[4][2] of 32x32 frags.
__global__ __launch_bounds__(512, 2)
void k_gemm(const int8_t* __restrict__ A8, const int8_t* __restrict__ B8,
            int* __restrict__ out, unsigned* __restrict__ maxslot) {
  __shared__ int8_t As[2][BM * BK];  // 16KB each
  __shared__ int8_t Bs[2][BN * BK];

  const int tid  = threadIdx.x;
  const int lane = tid & 63;
  const int w    = tid >> 6;
  const int wm   = w >> 2;  // 0..1 -> 128-row half
  const int wn   = w & 3;   // 0..3 -> 64-col slice

  // XCD-bijective swizzle: 512 wgs, 8 XCDs, 64-wg chunks (16 bm x 4 bn).
  const int orig = blockIdx.x;
  const int wgid = ((orig & 7) << 6) + (orig >> 3);
  const int bn = wgid & 3;
  const int bm = wgid >> 2;
  const int m0 = bm * BM;
  const int n0 = bn * BN;

  i32x16 acc[4][2];
#pragma unroll
  for (int i = 0; i < 4; ++i)
#pragma unroll
    for (int j = 0; j < 2; ++j) acc[i][j] = 0;

  // LDS layout (both tiles): physical byte p holds logical element at
  // (row = p>>6, col = (p&63) ^ ((row>>1 & 3)<<4)).  gload_lds dest is
  // linear; swizzle rides on the per-lane SOURCE address (rule 21).
  auto stage = [&](int buf, int kt) {
    const int k0 = kt * BK;
#pragma unroll
    for (int q = 0; q < 2; ++q) {
      const int p   = (w * 2 + q) * 1024 + lane * 16;
      const int row = p >> 6;
      const int col = (p & 63) ^ (((row >> 1) & 3) << 4);
      __builtin_amdgcn_global_load_lds(
          (const __attribute__((address_space(1))) void*)(A8 + (size_t)(m0 + row) * KK + k0 + col),
          (__attribute__((address_space(3))) void*)(&As[buf][(w * 2 + q) * 1024]),
          16, 0, 0);
      __builtin_amdgcn_global_load_lds(
          (const __attribute__((address_space(1))) void*)(B8 + (size_t)(n0 + row) * KK + k0 + col),
          (__attribute__((address_space(3))) void*)(&Bs[buf][(w * 2 + q) * 1024]),
          16, 0, 0);
    }
  };

  // 16 MFMA per wave per K-tile; 12 swizzled ds_read_b128 (conflict-free:
  // per 8-row group the XOR + row-parity covers all 32 banks).
  auto compute = [&](int buf) {
#pragma unroll
    for (int ks = 0; ks < 2; ++ks) {
      i32x4 af[4], bf[2];
#pragma unroll
      for (int ni = 0; ni < 2; ++ni) {
        const int row = wn * 64 + ni * 32 + (lane & 31);
        const int a = row * BK +
            ((ks * 32 + ((lane >> 5) << 4)) ^ (((row >> 1) & 3) << 4));
        bf[ni] = *(const i32x4*)(&Bs[buf][a]);
      }
#pragma unroll
      for (int mi = 0; mi < 4; ++mi) {
        const int row = wm * 128 + mi * 32 + (lane & 31);
        const int a = row * BK +
            ((ks * 32 + ((lane >> 5) << 4)) ^ (((row >> 1) & 3) << 4));
        af[mi] = *(const i32x4*)(&As[buf][a]);
      }
      __builtin_amdgcn_s_setprio(1);
#pragma unroll
      for (int mi = 0; mi < 4; ++mi)
#pragma unroll
        for (int ni = 0; ni < 2; ++ni)
          acc[mi][ni] = __builtin_amdgcn_mfma_i32_32x32x32_i8(
              af[mi], bf[ni], acc[mi][ni], 0, 0, 0);
      __builtin_amdgcn_s_setprio(0);
    }
  };

  stage(0, 0);
  __syncthreads();
  for (int kt = 0; kt < NKT; ++kt) {
    if (kt + 1 < NKT) stage((kt + 1) & 1, kt + 1);  // prefetch next tile
    compute(kt & 1);
    __syncthreads();  // drain; other resident block's compute covers it
  }

  // Wave max of |acc| -> atomicMax
  int mx = 0;
#pragma unroll
  for (int mi = 0; mi < 4; ++mi)
#pragma unroll
    for (int ni = 0; ni < 2; ++ni)
#pragma unroll
      for (int rg = 0; rg < 16; ++rg) {
        int x = acc[mi][ni][rg];
        int a = x < 0 ? -x : x;
        mx = a > mx ? a : mx;
      }
#pragma unroll
  for (int off = 32; off >= 1; off >>= 1) {
    int o = __shfl_xor(mx, off);
    mx = o > mx ? o : mx;
  }
  if (lane == 0) atomicMax(maxslot, (unsigned)mx);

  // Store raw acc (C/D map: col=lane&31, row=(rg&3)+8*(rg>>2)+4*(lane>>5))
#pragma unroll
  for (int mi = 0; mi < 4; ++mi)
#pragma unroll
    for (int ni = 0; ni < 2; ++ni) {
      const int mbase = m0 + wm * 128 + mi * 32;
      const int ncol  = n0 + wn * 64 + ni * 32 + (lane & 31);
#pragma unroll
      for (int rg = 0; rg < 16; ++rg) {
        const int mrow = mbase + (rg & 3) + ((rg >> 2) << 3) + ((lane >> 5) << 2);
        out[(size_t)mrow * NN + ncol] = acc[mi][ni][rg];
      }
    }
}

// Fallback (ws too small): reg-staged int32 GEMM, 128x128 tile, BK=128.
__global__ __launch_bounds__(256, 2)
void k_gemm_fb(const int* __restrict__ A32, const int* __restrict__ B32,
               int* __restrict__ out, unsigned* __restrict__ maxslot) {
  __shared__ int8_t As[128 * 128];
  __shared__ int8_t Bs[128 * 128];
  const int tid = threadIdx.x, lane = tid & 63, w = tid >> 6;
  const int wr = w >> 1, wc = w & 1;
  const int bn = blockIdx.x & 7, bm = blockIdx.x >> 3;
  const int m0 = bm * 128, n0 = bn * 128;
  i32x16 acc[2][2];
#pragma unroll
  for (int i = 0; i < 2; ++i)
#pragma unroll
    for (int j = 0; j < 2; ++j) acc[i][j] = 0;
  for (int kt = 0; kt < 8; ++kt) {
    const int k0 = kt * 128;
    __syncthreads();
#pragma unroll
    for (int j = 0; j < 4; ++j) {
      const int fb = (j * 256 + tid) * 16;
      const int row = fb >> 7;
      const int swz = fb ^ ((row & 7) << 4);
      const int col = fb & 127;
      const int* sa = A32 + (size_t)(m0 + row) * KK + k0 + col;
      const int* sb = B32 + (size_t)(n0 + row) * KK + k0 + col;
      i32x4 av, bv;
#pragma unroll
      for (int t = 0; t < 4; ++t) {
        i32x4 ta = ((const i32x4*)sa)[t];
        i32x4 tb = ((const i32x4*)sb)[t];
        av[t] = pack4(ta[0], ta[1], ta[2], ta[3]);
        bv[t] = pack4(tb[0], tb[1], tb[2], tb[3]);
      }
      *(i32x4*)(As + swz) = av;
      *(i32x4*)(Bs + swz) = bv;
    }
    __syncthreads();
#pragma unroll
    for (int ks = 0; ks < 4; ++ks) {
      i32x4 af[2], bf[2];
#pragma unroll
      for (int mi = 0; mi < 2; ++mi) {
        const int row = wr * 64 + mi * 32 + (lane & 31);
        int a = row * 128 + ks * 32 + ((lane >> 5) << 4);
        a ^= (row & 7) << 4;
        af[mi] = *(const i32x4*)(As + a);
      }
#pragma unroll
      for (int ni = 0; ni < 2; ++ni) {
        const int row = wc * 64 + ni * 32 + (lane & 31);
        int a = row * 128 + ks * 32 + ((lane >> 5) << 4);
        a ^= (row & 7) << 4;
        bf[ni] = *(const i32x4*)(Bs + a);
      }
#pragma unroll
      for (int mi = 0; mi < 2; ++mi)
#pragma unroll
        for (int ni = 0; ni < 2; ++ni)
          acc[mi][ni] = __builtin_amdgcn_mfma_i32_32x32x32_i8(
              af[mi], bf[ni], acc[mi][ni], 0, 0, 0);
    }
  }
  int mx = 0;
#pragma unroll
  for (int mi = 0; mi < 2; ++mi)
#pragma unroll
    for (int ni = 0; ni < 2; ++ni)
#pragma unroll
      for (int rg = 0; rg < 16; ++rg) {
        int x = acc[mi][ni][rg];
        int a = x < 0 ? -x : x;
        mx = a > mx ? a : mx;
      }
#pragma unroll
  for (int off = 32; off >= 1; off >>= 1) {
    int o = __shfl_xor(mx, off);
    mx = o > mx ? o : mx;
  }
  if (lane == 0) atomicMax(maxslot, (unsigned)mx);
#pragma unroll
  for (int mi = 0; mi < 2; ++mi)
#pragma unroll
    for (int ni = 0; ni < 2; ++ni) {
      const int mbase = m0 + wr * 64 + mi * 32;
      const int ncol = n0 + wc * 64 + ni * 32 + (lane & 31);
#pragma unroll
      for (int rg = 0; rg < 16; ++rg) {
        const int mrow = mbase + (rg & 3) + ((rg >> 2) << 3) + ((lane >> 5) << 2);
        out[(size_t)mrow * NN + ncol] = acc[mi][ni][rg];
      }
    }
}

// In-place requantize d_out[0..M*N) using max from maxslot. BW-bound.
__global__ __launch_bounds__(256)
void k_requant(int* __restrict__ out, const unsigned* __restrict__ maxslot) {
  const unsigned r = *maxslot;
  const int bits  = (r <= 1u) ? 0 : (32 - __clz((int)(r - 1u)));
  const int shift = bits - 7;  // BITWIDTH = 7
  const size_t n = (size_t)MM * NN;
  size_t i = ((size_t)blockIdx.x * blockDim.x + threadIdx.x) * 4;
  const size_t stride = (size_t)gridDim.x * blockDim.x * 4;
  if (shift > 0) {
    for (; i < n; i += stride) {
      i32x4 v = *(i32x4*)(out + i);
#pragma unroll
      for (int j = 0; j < 4; ++j) {
        const int x = v[j];
        int t = (x >> shift) + ((x >> (shift - 1)) & 1);
        v[j] = t > 127 ? 127 : (t < -127 ? -127 : t);
      }
      *(i32x4*)(out + i) = v;
    }
  } else {
    for (; i < n; i += stride) {
      i32x4 v = *(i32x4*)(out + i);
#pragma unroll
      for (int j = 0; j < 4; ++j) v[j] = (int)(int8_t)v[j];
      *(i32x4*)(out + i) = v;
    }
  }
}

__global__ void k_final(int* __restrict__ out, const int* __restrict__ exp_in,
                        const int* __restrict__ wexp) {
  if (threadIdx.x == 0) {
    const unsigned r = *(const unsigned*)(out + (size_t)MM * NN);
    const int bits  = (r <= 1u) ? 0 : (32 - __clz((int)(r - 1u)));
    const int shift = bits - 7;
    out[(size_t)MM * NN] = *exp_in + *wexp + (shift > 0 ? shift : 0);
  }
}

extern "C" void kernel_launch(void* const* d_in, const int* in_sizes, int n_in,
                              void* d_out, int out_size, void* d_ws, size_t ws_size,
                              hipStream_t stream) {
  const int* act    = (const int*)d_in[0];
  const int* wgt    = (const int*)d_in[1];
  const int* exp_in = (const int*)d_in[2];
  const int* wexp   = (const int*)d_in[3];
  int* out          = (int*)d_out;
  unsigned* maxslot = (unsigned*)(out + (size_t)MM * NN);  // spare exp slot

  const size_t need = (size_t)(MM + NN) * KK + 256;

  k_init<<<1, 64, 0, stream>>>(maxslot);

  if (ws_size >= need) {
    int8_t* a8 = (int8_t*)d_ws;
    int8_t* w8 = a8 + (size_t)MM * KK;
    k_pack<<<2048, 256, 0, stream>>>(act, a8, MM * KK);
    k_pack<<<256, 256, 0, stream>>>(wgt, w8, NN * KK);
    const int grid = (MM / BM) * (NN / BN);  // 512
    k_gemm<<<grid, 512, 0, stream>>>(a8, w8, out, maxslot);
  } else {
    k_gemm_fb<<<(MM / 128) * (NN / 128), 256, 0, stream>>>(act, wgt, out, maxslot);
  }

  k_requant<<<4096, 256, 0, stream>>>(out, maxslot);
  k_final<<<1, 64, 0, stream>>>(out, exp_in, wexp);
}